// Round 22
// baseline (291.849 us; speedup 1.0000x reference)
//
#include <hip/hip_runtime.h>
#include <hip/hip_cooperative_groups.h>

namespace cg = cooperative_groups;

#define HW 256
#define HWMASK 255
#define CH 128
#define BATCH 8
#define NK 4
#define STRIP 16           // output rows per strip
#define NIN (STRIP + 6)    // input rows per strip

typedef float f32x4 __attribute__((ext_vector_type(4)));

__device__ __forceinline__ float rfl(float v) {
    union { float f; int i; } a, b;
    a.f = v;
    b.i = __builtin_amdgcn_readfirstlane(a.i);
    return b.f;
}

// ================= fused cooperative kernel =================
__global__ __launch_bounds__(256, 4) void fused_kernel(const float* __restrict__ x,
                                                       const float* __restrict__ guid,
                                                       const float* __restrict__ basis,
                                                       const float* __restrict__ w1,
                                                       const float* __restrict__ b1,
                                                       const float* __restrict__ w2,
                                                       const float* __restrict__ b2,
                                                       float* __restrict__ out,
                                                       float* __restrict__ g) {
    int bc = blockIdx.x;                  // 0..1023 plane id
    int tid = threadIdx.x;

    // ---- phase 1: mean of guidance plane bc ----
    {
        const float4* p = (const float4*)(guid + (size_t)bc * (HW * HW));
        float s = 0.f;
        #pragma unroll 4
        for (int i = tid; i < (HW * HW / 4); i += 256) {
            float4 v = p[i];
            s += (v.x + v.y) + (v.z + v.w);
        }
        for (int off = 32; off; off >>= 1) s += __shfl_down(s, off, 64);
        __shared__ float red[4];
        if ((tid & 63) == 0) red[tid >> 6] = s;
        __syncthreads();
        if (tid == 0)
            atomicExch(&g[bc], ((red[0] + red[1]) + (red[2] + red[3])) * (1.0f / 65536.0f));
    }
    cg::this_grid().sync();

    // ---- phase 2: redundant MLP + this plane's flipped taps ----
    __shared__ float gs[BATCH * CH];
    __shared__ float h1[BATCH * 32];
    __shared__ float lg[BATCH * NK];
    __shared__ float wts[BATCH * NK];
    __shared__ float tap[49];
    for (int i = tid; i < BATCH * CH; i += 256) gs[i] = g[i];
    __syncthreads();
    {
        int b = tid >> 5, j = tid & 31;
        float acc = b1[j];
        #pragma unroll 4
        for (int c = 0; c < CH; ++c) acc += gs[b * CH + c] * w1[j * CH + c];
        h1[tid] = fmaxf(acc, 0.f);
    }
    __syncthreads();
    if (tid < BATCH * NK) {
        int b = tid >> 2, k = tid & 3;
        float acc = b2[k];
        #pragma unroll
        for (int j = 0; j < 32; ++j) acc += h1[b * 32 + j] * w2[k * 32 + j];
        lg[tid] = acc;
    }
    __syncthreads();
    if (tid < BATCH) {
        int b = tid;
        float m = lg[b * 4];
        for (int k = 1; k < 4; ++k) m = fmaxf(m, lg[b * 4 + k]);
        float e[4], s = 0.f;
        for (int k = 0; k < 4; ++k) { e[k] = expf(lg[b * 4 + k] - m); s += e[k]; }
        float inv = 1.0f / s;
        for (int k = 0; k < 4; ++k) wts[b * 4 + k] = e[k] * inv;
    }
    __syncthreads();
    {
        int b = bc >> 7, c = bc & 127;
        if (tid < 49) {
            float acc = 0.f;
            #pragma unroll
            for (int k = 0; k < NK; ++k)
                acc += wts[b * NK + k] * basis[(k * CH + c) * 49 + tid];
            tap[48 - tid] = acc;          // flipped
        }
    }
    __syncthreads();
    float d[49];
    #pragma unroll
    for (int i = 0; i < 49; ++i) d[i] = rfl(tap[i]);   // uniform -> SGPR

    // ---- phase 3: conv; wave ty covers rows [64*ty, 64*ty+64) as 4 strips ----
    const float* xp = x + (size_t)bc * (HW * HW);
    float* op = out + (size_t)bc * (HW * HW);
    int lane = tid & 63, ty = tid >> 6;
    int col = 4 * lane;
    int lL = (lane + 63) & 63;
    int lR = (lane + 1) & 63;

    #pragma unroll 1
    for (int st = 0; st < 4; ++st) {
        int yb = 64 * ty + 16 * st;

        float4 pf[4];
        #pragma unroll
        for (int k = 0; k < 4; ++k)
            pf[k] = *(const float4*)(xp + (((yb + k - 3) & HWMASK) * HW) + col);

        float acc[7][4] = {};
        #pragma unroll
        for (int i = 0; i < NIN; ++i) {
            float4 Q = pf[i & 3];
            if (i + 4 < NIN)
                pf[i & 3] = *(const float4*)(xp + (((yb + i + 1) & HWMASK) * HW) + col);

            float4 L, R;
            L.x = __shfl(Q.x, lL, 64); L.y = __shfl(Q.y, lL, 64);
            L.z = __shfl(Q.z, lL, 64); L.w = __shfl(Q.w, lL, 64);
            R.x = __shfl(Q.x, lR, 64); R.y = __shfl(Q.y, lR, 64);
            R.z = __shfl(Q.z, lR, 64); R.w = __shfl(Q.w, lR, 64);
            float v[12] = {L.x, L.y, L.z, L.w, Q.x, Q.y, Q.z, Q.w, R.x, R.y, R.z, R.w};

            #pragma unroll
            for (int ii = 0; ii < 7; ++ii) {
                int o = i - ii;
                if (o >= 0 && o < STRIP) {
                    const int s = ((unsigned)o) % 7;
                    #pragma unroll
                    for (int q = 0; q < 4; ++q) {
                        #pragma unroll
                        for (int jj = 0; jj < 7; ++jj)
                            acc[s][q] += d[ii * 7 + jj] * v[q + jj + 1];
                    }
                }
            }
            if (i >= 6) {
                const int o = i - 6;
                const int s = ((unsigned)o) % 7;
                f32x4 ov = {acc[s][0], acc[s][1], acc[s][2], acc[s][3]};
                __builtin_nontemporal_store(ov, (f32x4*)(op + (yb + o) * HW + col));
                acc[s][0] = 0.f; acc[s][1] = 0.f; acc[s][2] = 0.f; acc[s][3] = 0.f;
            }
        }
    }
}

// ================= fallback path (R20, proven 169.6 us) =================
__global__ __launch_bounds__(256) void mean1_kernel(const float* __restrict__ guid,
                                                    float* __restrict__ partial) {
    int blk = blockIdx.x;
    const float4* p = (const float4*)(guid + (size_t)blk * 16384);
    float s = 0.f;
    for (int i = threadIdx.x; i < 4096; i += 256) {
        float4 v = p[i];
        s += (v.x + v.y) + (v.z + v.w);
    }
    for (int off = 32; off; off >>= 1) s += __shfl_down(s, off, 64);
    __shared__ float red[4];
    if ((threadIdx.x & 63) == 0) red[threadIdx.x >> 6] = s;
    __syncthreads();
    if (threadIdx.x == 0) partial[blk] = (red[0] + red[1]) + (red[2] + red[3]);
}

__global__ __launch_bounds__(256) void mlpdyn_kernel(const float* __restrict__ partial,
                                                     const float* __restrict__ w1,
                                                     const float* __restrict__ b1,
                                                     const float* __restrict__ w2,
                                                     const float* __restrict__ b2,
                                                     const float* __restrict__ basis,
                                                     float* __restrict__ dynF) {
    __shared__ float gs[BATCH * CH];
    __shared__ float h1[BATCH * 32];
    __shared__ float lg[BATCH * NK];
    __shared__ float wt[BATCH * NK];
    int t = threadIdx.x;
    for (int i = t; i < BATCH * CH; i += 256) {
        float4 v = *(const float4*)(partial + i * 4);
        gs[i] = ((v.x + v.y) + (v.z + v.w)) * (1.0f / 65536.0f);
    }
    __syncthreads();
    {
        int b = t >> 5, j = t & 31;
        float acc = b1[j];
        #pragma unroll 4
        for (int c = 0; c < CH; ++c) acc += gs[b * CH + c] * w1[j * CH + c];
        h1[b * 32 + j] = fmaxf(acc, 0.f);
    }
    __syncthreads();
    if (t < BATCH * NK) {
        int b = t >> 2, k = t & 3;
        float acc = b2[k];
        #pragma unroll
        for (int j = 0; j < 32; ++j) acc += h1[b * 32 + j] * w2[k * 32 + j];
        lg[b * NK + k] = acc;
    }
    __syncthreads();
    if (t < BATCH) {
        int b = t;
        float m = lg[b * 4];
        for (int k = 1; k < 4; ++k) m = fmaxf(m, lg[b * 4 + k]);
        float e[4], s = 0.f;
        for (int k = 0; k < 4; ++k) { e[k] = expf(lg[b * 4 + k] - m); s += e[k]; }
        float inv = 1.0f / s;
        for (int k = 0; k < 4; ++k) wt[b * 4 + k] = e[k] * inv;
    }
    __syncthreads();

    int idx = blockIdx.x * 256 + t;
    if (idx >= BATCH * CH * 49) return;
    int ij = idx % 49;
    int bc = idx / 49;
    int c = bc % CH;
    int b = bc / CH;
    float acc = 0.f;
    #pragma unroll
    for (int k = 0; k < NK; ++k)
        acc += wt[b * NK + k] * basis[(k * CH + c) * 49 + ij];
    dynF[bc * 49 + (48 - ij)] = acc;
}

__global__ __launch_bounds__(256) void conv_kernel(const float* __restrict__ x,
                                                   const float* __restrict__ dynF,
                                                   float* __restrict__ out) {
    int bc = blockIdx.x;
    const float* xp = x + (size_t)bc * (HW * HW);
    float* op = out + (size_t)bc * (HW * HW);
    int tid = threadIdx.x;
    int lane = tid & 63, ty = tid >> 6;
    int yb = blockIdx.y * (4 * STRIP) + ty * STRIP;

    const float* df = dynF + bc * 49;
    float d[49];
    #pragma unroll
    for (int i = 0; i < 49; ++i) d[i] = df[i];

    int col = 4 * lane;
    int lL = (lane + 63) & 63;
    int lR = (lane + 1) & 63;

    float4 pf[4];
    #pragma unroll
    for (int k = 0; k < 4; ++k)
        pf[k] = *(const float4*)(xp + (((yb + k - 3) & HWMASK) * HW) + col);

    float acc[7][4] = {};
    #pragma unroll
    for (int i = 0; i < NIN; ++i) {
        float4 Q = pf[i & 3];
        if (i + 4 < NIN)
            pf[i & 3] = *(const float4*)(xp + (((yb + i + 1) & HWMASK) * HW) + col);

        float4 L, R;
        L.x = __shfl(Q.x, lL, 64); L.y = __shfl(Q.y, lL, 64);
        L.z = __shfl(Q.z, lL, 64); L.w = __shfl(Q.w, lL, 64);
        R.x = __shfl(Q.x, lR, 64); R.y = __shfl(Q.y, lR, 64);
        R.z = __shfl(Q.z, lR, 64); R.w = __shfl(Q.w, lR, 64);
        float v[12] = {L.x, L.y, L.z, L.w, Q.x, Q.y, Q.z, Q.w, R.x, R.y, R.z, R.w};

        #pragma unroll
        for (int ii = 0; ii < 7; ++ii) {
            int o = i - ii;
            if (o >= 0 && o < STRIP) {
                const int s = ((unsigned)o) % 7;
                #pragma unroll
                for (int q = 0; q < 4; ++q) {
                    #pragma unroll
                    for (int jj = 0; jj < 7; ++jj)
                        acc[s][q] += d[ii * 7 + jj] * v[q + jj + 1];
                }
            }
        }
        if (i >= 6) {
            const int o = i - 6;
            const int s = ((unsigned)o) % 7;
            f32x4 ov = {acc[s][0], acc[s][1], acc[s][2], acc[s][3]};
            __builtin_nontemporal_store(ov, (f32x4*)(op + (yb + o) * HW + col));
            acc[s][0] = 0.f; acc[s][1] = 0.f; acc[s][2] = 0.f; acc[s][3] = 0.f;
        }
    }
}

extern "C" void kernel_launch(void* const* d_in, const int* in_sizes, int n_in,
                              void* d_out, int out_size, void* d_ws, size_t ws_size,
                              hipStream_t stream) {
    const float* x        = (const float*)d_in[0];
    const float* guidance = (const float*)d_in[1];
    const float* basis    = (const float*)d_in[2];
    const float* w1       = (const float*)d_in[3];
    const float* b1       = (const float*)d_in[4];
    const float* w2       = (const float*)d_in[5];
    const float* b2       = (const float*)d_in[6];
    float* out = (float*)d_out;
    float* ws  = (float*)d_ws;

    float* g = ws;                        // 1024 floats (coop path)

    void* args[] = {(void*)&x, (void*)&guidance, (void*)&basis, (void*)&w1,
                    (void*)&b1, (void*)&w2, (void*)&b2, (void*)&out, (void*)&g};
    hipError_t err = hipLaunchCooperativeKernel((void*)fused_kernel, dim3(BATCH * CH),
                                                dim3(256), args, 0, stream);
    if (err != hipSuccess) {
        // fallback: proven 3-kernel path (R20)
        float* partial = ws;              // 4096
        float* dynF    = ws + 4096;       // 50176
        mean1_kernel<<<4096, 256, 0, stream>>>(guidance, partial);
        mlpdyn_kernel<<<(BATCH * CH * 49 + 255) / 256, 256, 0, stream>>>(partial, w1, b1, w2, b2, basis, dynF);
        conv_kernel<<<dim3(BATCH * CH, HW / (4 * STRIP)), 256, 0, stream>>>(x, dynF, out);
    }
}

// Round 23
// 167.054 us; speedup vs baseline: 1.7470x; 1.7470x over previous
//
#include <hip/hip_runtime.h>

#define HW 256
#define HWMASK 255
#define CH 128
#define BATCH 8
#define NK 4
#define STRIP 16           // output rows per strip
#define NIN (STRIP + 6)    // input rows per strip

typedef float f32x4 __attribute__((ext_vector_type(4)));

// ---------------- Kernel A1: partial sums of guidance ----------------
__global__ __launch_bounds__(256) void mean1_kernel(const float* __restrict__ guid,
                                                    float* __restrict__ partial) {
    int blk = blockIdx.x;
    const float4* p = (const float4*)(guid + (size_t)blk * 16384);
    float s = 0.f;
    for (int i = threadIdx.x; i < 4096; i += 256) {
        float4 v = p[i];
        s += (v.x + v.y) + (v.z + v.w);
    }
    for (int off = 32; off; off >>= 1) s += __shfl_down(s, off, 64);
    __shared__ float red[4];
    if ((threadIdx.x & 63) == 0) red[threadIdx.x >> 6] = s;
    __syncthreads();
    if (threadIdx.x == 0) partial[blk] = (red[0] + red[1]) + (red[2] + red[3]);
}

// ---------------- Kernel B: fused means+MLP+softmax+dyn-blend ----------------
__global__ __launch_bounds__(256) void mlpdyn_kernel(const float* __restrict__ partial,
                                                     const float* __restrict__ w1,
                                                     const float* __restrict__ b1,
                                                     const float* __restrict__ w2,
                                                     const float* __restrict__ b2,
                                                     const float* __restrict__ basis,
                                                     float* __restrict__ dynF) {
    __shared__ float gs[BATCH * CH];
    __shared__ float h1[BATCH * 32];
    __shared__ float lg[BATCH * NK];
    __shared__ float wt[BATCH * NK];
    int t = threadIdx.x;
    for (int i = t; i < BATCH * CH; i += 256) {
        float4 v = *(const float4*)(partial + i * 4);
        gs[i] = ((v.x + v.y) + (v.z + v.w)) * (1.0f / 65536.0f);
    }
    __syncthreads();
    {
        int b = t >> 5, j = t & 31;
        float acc = b1[j];
        #pragma unroll 4
        for (int c = 0; c < CH; ++c) acc += gs[b * CH + c] * w1[j * CH + c];
        h1[b * 32 + j] = fmaxf(acc, 0.f);
    }
    __syncthreads();
    if (t < BATCH * NK) {
        int b = t >> 2, k = t & 3;
        float acc = b2[k];
        #pragma unroll
        for (int j = 0; j < 32; ++j) acc += h1[b * 32 + j] * w2[k * 32 + j];
        lg[b * NK + k] = acc;
    }
    __syncthreads();
    if (t < BATCH) {
        int b = t;
        float m = lg[b * 4];
        for (int k = 1; k < 4; ++k) m = fmaxf(m, lg[b * 4 + k]);
        float e[4], s = 0.f;
        for (int k = 0; k < 4; ++k) { e[k] = expf(lg[b * 4 + k] - m); s += e[k]; }
        float inv = 1.0f / s;
        for (int k = 0; k < 4; ++k) wt[b * 4 + k] = e[k] * inv;
    }
    __syncthreads();

    int idx = blockIdx.x * 256 + t;
    if (idx >= BATCH * CH * 49) return;
    int ij = idx % 49;
    int bc = idx / 49;
    int c = bc % CH;
    int b = bc / CH;
    float acc = 0.f;
    #pragma unroll
    for (int k = 0; k < NK; ++k)
        acc += wt[b * NK + k] * basis[(k * CH + c) * 49 + ij];
    dynF[bc * 49 + (48 - ij)] = acc;
}

// ---------------- Kernel D: circular depthwise 7x7 conv, 2-strip ILP ----------------
// No LDS data path, no barriers. Wave = 64 lanes x 4 cols = full 256-px row.
// Each wave processes TWO independent 16-row strips (yb and yb+64) with separate
// prefetch/accumulator sets -> 2x independent FMA+load chains per wave to fill
// stall cycles. All pf/acc indices compile-time (full unroll of the 22-iter loop).
__global__ __launch_bounds__(256) void conv_kernel(const float* __restrict__ x,
                                                   const float* __restrict__ dynF,
                                                   float* __restrict__ out) {
    int bc = blockIdx.x;                  // 0..1023 plane id
    const float* xp = x + (size_t)bc * (HW * HW);
    float* op = out + (size_t)bc * (HW * HW);
    int tid = threadIdx.x;
    int lane = tid & 63, ty = tid >> 6;
    int yb = blockIdx.y * 128 + ty * STRIP;   // strip A
    int yc = yb + 64;                          // strip B

    // filter taps: block-uniform address -> scalar loads into SGPRs
    const float* df = dynF + bc * 49;
    float d[49];
    #pragma unroll
    for (int i = 0; i < 49; ++i) d[i] = df[i];

    int col = 4 * lane;
    int lL = (lane + 63) & 63;
    int lR = (lane + 1) & 63;

    // prologue: prefetch rows 0..3 of both windows
    float4 pa[4], pb[4];
    #pragma unroll
    for (int k = 0; k < 4; ++k) {
        pa[k] = *(const float4*)(xp + (((yb + k - 3) & HWMASK) * HW) + col);
        pb[k] = *(const float4*)(xp + (((yc + k - 3) & HWMASK) * HW) + col);
    }

    float aA[7][4] = {};
    float aB[7][4] = {};
    #pragma unroll
    for (int i = 0; i < NIN; ++i) {
        float4 QA = pa[i & 3];
        float4 QB = pb[i & 3];
        if (i + 4 < NIN) {
            pa[i & 3] = *(const float4*)(xp + (((yb + i + 1) & HWMASK) * HW) + col);
            pb[i & 3] = *(const float4*)(xp + (((yc + i + 1) & HWMASK) * HW) + col);
        }

        float4 LA, RA, LB, RB;
        LA.x = __shfl(QA.x, lL, 64); LA.y = __shfl(QA.y, lL, 64);
        LA.z = __shfl(QA.z, lL, 64); LA.w = __shfl(QA.w, lL, 64);
        RA.x = __shfl(QA.x, lR, 64); RA.y = __shfl(QA.y, lR, 64);
        RA.z = __shfl(QA.z, lR, 64); RA.w = __shfl(QA.w, lR, 64);
        LB.x = __shfl(QB.x, lL, 64); LB.y = __shfl(QB.y, lL, 64);
        LB.z = __shfl(QB.z, lL, 64); LB.w = __shfl(QB.w, lL, 64);
        RB.x = __shfl(QB.x, lR, 64); RB.y = __shfl(QB.y, lR, 64);
        RB.z = __shfl(QB.z, lR, 64); RB.w = __shfl(QB.w, lR, 64);
        float vA[12] = {LA.x, LA.y, LA.z, LA.w, QA.x, QA.y, QA.z, QA.w, RA.x, RA.y, RA.z, RA.w};
        float vB[12] = {LB.x, LB.y, LB.z, LB.w, QB.x, QB.y, QB.z, QB.w, RB.x, RB.y, RB.z, RB.w};

        #pragma unroll
        for (int ii = 0; ii < 7; ++ii) {
            int o = i - ii;
            if (o >= 0 && o < STRIP) {
                const int s = ((unsigned)o) % 7;
                #pragma unroll
                for (int q = 0; q < 4; ++q) {
                    #pragma unroll
                    for (int jj = 0; jj < 7; ++jj) {
                        aA[s][q] += d[ii * 7 + jj] * vA[q + jj + 1];
                        aB[s][q] += d[ii * 7 + jj] * vB[q + jj + 1];
                    }
                }
            }
        }
        if (i >= 6) {
            const int o = i - 6;
            const int s = ((unsigned)o) % 7;
            f32x4 oA = {aA[s][0], aA[s][1], aA[s][2], aA[s][3]};
            f32x4 oB = {aB[s][0], aB[s][1], aB[s][2], aB[s][3]};
            __builtin_nontemporal_store(oA, (f32x4*)(op + (yb + o) * HW + col));
            __builtin_nontemporal_store(oB, (f32x4*)(op + (yc + o) * HW + col));
            aA[s][0] = 0.f; aA[s][1] = 0.f; aA[s][2] = 0.f; aA[s][3] = 0.f;
            aB[s][0] = 0.f; aB[s][1] = 0.f; aB[s][2] = 0.f; aB[s][3] = 0.f;
        }
    }
}

extern "C" void kernel_launch(void* const* d_in, const int* in_sizes, int n_in,
                              void* d_out, int out_size, void* d_ws, size_t ws_size,
                              hipStream_t stream) {
    const float* x        = (const float*)d_in[0];
    const float* guidance = (const float*)d_in[1];
    const float* basis    = (const float*)d_in[2];
    const float* w1       = (const float*)d_in[3];
    const float* b1       = (const float*)d_in[4];
    const float* w2       = (const float*)d_in[5];
    const float* b2       = (const float*)d_in[6];
    float* out = (float*)d_out;
    float* ws  = (float*)d_ws;

    float* partial = ws;                  // 4096
    float* dynF    = ws + 4096;           // 50176

    mean1_kernel<<<4096, 256, 0, stream>>>(guidance, partial);
    mlpdyn_kernel<<<(BATCH * CH * 49 + 255) / 256, 256, 0, stream>>>(partial, w1, b1, w2, b2, basis, dynF);
    conv_kernel<<<dim3(BATCH * CH, 2), 256, 0, stream>>>(x, dynF, out);
}